// Round 4
// baseline (693.656 us; speedup 1.0000x reference)
//
#include <hip/hip_runtime.h>
#include <stdint.h>

// BitNet MLP: x[65536,512] --i8gemm--> h --relu^2+SubLN+actquant--> h_q
//             --i8gemm--> out[65536,512].
// GEMM: 256x256 tile, BK=64, 8 waves (2Mx4N), per-wave 128x64 as 4x2 tiles of
// v_mfma_i32_32x32x32_i8 (2x ops per LDS byte vs 16x16x64 -> fixes the
// LDS-BW-bound regime measured in rounds 2/3). 2-phase LDS double-buffer,
// granule-XOR swizzle (conflict-free, verified 0 in round 3), global_load_lds.

typedef int v4i  __attribute__((ext_vector_type(4)));
typedef int v16i __attribute__((ext_vector_type(16)));

#define AS1(p) ((const __attribute__((address_space(1))) void*)(p))
#define AS3(p) ((__attribute__((address_space(3))) void*)(p))

static constexpr size_t OFF_PART = 256;
static constexpr size_t OFF_SX   = 8192;
static constexpr size_t OFF_RSQ  = OFF_SX   + 262144;
static constexpr size_t OFF_S2   = OFF_RSQ  + 262144;
static constexpr size_t OFF_INV2 = OFF_S2   + 262144;
static constexpr size_t OFF_WUQ  = OFF_INV2 + 262144;
static constexpr size_t OFF_WDQ  = OFF_WUQ  + 1048576;
static constexpr size_t OFF_XQ   = OFF_WDQ  + 1048576;
static constexpr size_t OFF_HQ   = OFF_XQ   + 33554432;
static constexpr size_t OFF_SS   = OFF_HQ   + 134217728;
static constexpr size_t OFF_MM   = OFF_SS   + 8388608;

// ---------------- weight |w| partial sums (deterministic, fp64) -------------
__global__ void wabs_partial(const float* __restrict__ w, double* __restrict__ part)
{
    int t = threadIdx.x, bid = blockIdx.x;
    const float4* w4 = (const float4*)w;
    int base = bid * 256 + t;
    double s = 0.0;
    #pragma unroll
    for (int j = 0; j < 4; ++j) {
        float4 v = w4[base + j * 65536];
        s += (double)fabsf(v.x) + (double)fabsf(v.y)
           + (double)fabsf(v.z) + (double)fabsf(v.w);
    }
    #pragma unroll
    for (int off = 32; off > 0; off >>= 1) s += __shfl_down(s, off);
    __shared__ double ps[4];
    int l = t & 63, wv = t >> 6;
    if (l == 0) ps[wv] = s;
    __syncthreads();
    if (t == 0) part[bid] = ((ps[0] + ps[1]) + ps[2]) + ps[3];
}

__global__ void finalize_sums(const double* __restrict__ part, double* __restrict__ sums)
{
    int t = threadIdx.x;
    double a = part[t];
    double b = part[256 + t];
    #pragma unroll
    for (int off = 32; off > 0; off >>= 1) {
        a += __shfl_down(a, off);
        b += __shfl_down(b, off);
    }
    __shared__ double pa[4], pb[4];
    int l = t & 63, wv = t >> 6;
    if (l == 0) { pa[wv] = a; pb[wv] = b; }
    __syncthreads();
    if (t == 0) {
        sums[0] = ((pa[0] + pa[1]) + pa[2]) + pa[3];
        sums[1] = ((pb[0] + pb[1]) + pb[2]) + pb[3];
    }
}

// ---------------- ternary weight quantization -------------------------------
__global__ void wquant(const float* __restrict__ w, const double* __restrict__ sum,
                       signed char* __restrict__ wq)
{
    int i = blockIdx.x * blockDim.x + threadIdx.x;
    if (i >= 262144) return;
    float mean  = (float)(*sum) * (1.0f / 1048576.0f);
    float scale = 1.0f / fmaxf(mean, 1e-5f);
    float4 v = ((const float4*)w)[i];
    int q0 = (int)fminf(fmaxf(rintf(v.x * scale), -1.f), 1.f);
    int q1 = (int)fminf(fmaxf(rintf(v.y * scale), -1.f), 1.f);
    int q2 = (int)fminf(fmaxf(rintf(v.z * scale), -1.f), 1.f);
    int q3 = (int)fminf(fmaxf(rintf(v.w * scale), -1.f), 1.f);
    unsigned pk = (q0 & 255) | ((q1 & 255) << 8) | ((q2 & 255) << 16) | ((q3 & 255) << 24);
    ((unsigned*)wq)[i] = pk;
}

// ---------------- activation quantization of x (per-token, H=512) -----------
__global__ void xquant(const float* __restrict__ x, signed char* __restrict__ xq,
                       float* __restrict__ inv_sx)
{
    int row = blockIdx.x * 4 + (threadIdx.x >> 6);
    int l   = threadIdx.x & 63;
    const float* xr = x + (size_t)row * 512;
    float4 v0 = *(const float4*)(xr + l * 8);
    float4 v1 = *(const float4*)(xr + l * 8 + 4);
    float m = fmaxf(fmaxf(fmaxf(fabsf(v0.x), fabsf(v0.y)), fmaxf(fabsf(v0.z), fabsf(v0.w))),
                    fmaxf(fmaxf(fabsf(v1.x), fabsf(v1.y)), fmaxf(fabsf(v1.z), fabsf(v1.w))));
    #pragma unroll
    for (int off = 1; off < 64; off <<= 1) m = fmaxf(m, __shfl_xor(m, off));
    float mc = fmaxf(m, 1e-5f);
    float s  = 127.0f / mc;
    int q[8];
    q[0] = (int)fminf(fmaxf(rintf(v0.x * s), -128.f), 127.f);
    q[1] = (int)fminf(fmaxf(rintf(v0.y * s), -128.f), 127.f);
    q[2] = (int)fminf(fmaxf(rintf(v0.z * s), -128.f), 127.f);
    q[3] = (int)fminf(fmaxf(rintf(v0.w * s), -128.f), 127.f);
    q[4] = (int)fminf(fmaxf(rintf(v1.x * s), -128.f), 127.f);
    q[5] = (int)fminf(fmaxf(rintf(v1.y * s), -128.f), 127.f);
    q[6] = (int)fminf(fmaxf(rintf(v1.z * s), -128.f), 127.f);
    q[7] = (int)fminf(fmaxf(rintf(v1.w * s), -128.f), 127.f);
    uint2 pk;
    pk.x = (q[0] & 255) | ((q[1] & 255) << 8) | ((q[2] & 255) << 16) | ((q[3] & 255) << 24);
    pk.y = (q[4] & 255) | ((q[5] & 255) << 8) | ((q[6] & 255) << 16) | ((q[7] & 255) << 24);
    *(uint2*)(xq + (size_t)row * 512 + l * 8) = pk;
    if (l == 0) inv_sx[row] = mc * (1.0f / 127.0f);
}

// ---------------- per-row stats reduce --------------------------------------
__global__ void row_reduce(const float* __restrict__ ss_p, const float* __restrict__ mm_p,
                           float* __restrict__ rsq, float* __restrict__ s2,
                           float* __restrict__ inv2)
{
    int row = blockIdx.x * blockDim.x + threadIdx.x;
    float ss = 0.f, mm = 0.f;
    #pragma unroll
    for (int p = 0; p < 32; ++p) {
        ss += ss_p[(size_t)row * 32 + p];
        mm  = fmaxf(mm, mm_p[(size_t)row * 32 + p]);
    }
    float var  = ss * (1.0f / 2048.0f);
    float r    = 1.0f / sqrtf(var + 1e-6f);
    float maxy = fmaxf(r * mm, 1e-5f);
    rsq[row]  = r;
    s2[row]   = 127.0f / maxy;
    inv2[row] = maxy * (1.0f / 127.0f);
}

// ---------------- int8 GEMM: C[M,N] = A[M,K] * B[N,K]^T ---------------------
// 32x32x32 i8 MFMA.  LDS tile row = 64B = 4 granules of 16B, granule XOR
// swizzle g^(r&3): linear LDS dest, inverse-swizzled global source (rule #21).
// Fragment: lane l reads row (l&31), k-granule ks*2+(l>>5)  [same-family map
// as the verified 16x16x64 path; A/B share it so k-permutation cancels].
// C/D: col=lane&31, row=(reg&3)+8*(reg>>2)+4*(lane>>5)  [m74/m101 verified].

#define COMPUTE(P)                                                             \
  {                                                                            \
    const char* Ab = &lds[P][0][0];                                            \
    const char* Bb = &lds[P][1][0];                                            \
    _Pragma("unroll")                                                          \
    for (int ks = 0; ks < 2; ++ks) {                                           \
      v4i af[4]; v4i bf[2];                                                    \
      _Pragma("unroll")                                                        \
      for (int m = 0; m < 4; ++m) {                                            \
        int r  = wr * 128 + m * 32 + lr;                                       \
        int eg = (ks * 2 + lh) ^ (r & 3);                                      \
        af[m] = *(const v4i*)(Ab + r * 64 + eg * 16);                          \
      }                                                                        \
      _Pragma("unroll")                                                        \
      for (int n = 0; n < 2; ++n) {                                            \
        int r  = wc * 64 + n * 32 + lr;                                        \
        int eg = (ks * 2 + lh) ^ (r & 3);                                      \
        bf[n] = *(const v4i*)(Bb + r * 64 + eg * 16);                          \
      }                                                                        \
      _Pragma("unroll")                                                        \
      for (int m = 0; m < 4; ++m)                                              \
        _Pragma("unroll")                                                      \
        for (int n = 0; n < 2; ++n)                                            \
          acc[m][n] = __builtin_amdgcn_mfma_i32_32x32x32_i8(                   \
              af[m], bf[n], acc[m][n], 0, 0, 0);                               \
    }                                                                          \
  }

template<int K, int N, int EPI>
__global__ __launch_bounds__(512, 2)
void gemm_i8(const signed char* __restrict__ A,
             const signed char* __restrict__ B,
             const float* __restrict__ rowscale,
             const double* __restrict__ wsum,
             const float* __restrict__ g,
             const float* __restrict__ rsq,
             const float* __restrict__ s2,
             float* __restrict__ st_ss,
             float* __restrict__ st_mm,
             signed char* __restrict__ hq,
             float* __restrict__ out)
{
    constexpr int NKT = K / 64;
    constexpr int NBN = N / 256;
    __shared__ __align__(16) char lds[2][2][16384];   // [buf][A/B][256 rows x 64B]

    // bijective XCD-chunked block swizzle (m204)
    int nwg  = gridDim.x;
    int orig = blockIdx.x;
    int q8 = nwg >> 3, r8 = nwg & 7;
    int xcd = orig & 7, lin = orig >> 3;
    int swz = (xcd < r8 ? xcd * (q8 + 1) : r8 * (q8 + 1) + (xcd - r8) * q8) + lin;
    int mt = swz / NBN, nt = swz - mt * NBN;

    size_t mbase = (size_t)mt * 256;
    int    nbase = nt * 256;

    int t  = threadIdx.x;
    int l  = t & 63;
    int wid = t >> 6;
    int wr = wid >> 2, wc = wid & 3;      // 2 M-waves x 4 N-waves
    int lr = l & 31, lh = l >> 5;

    const signed char* Ag = A + mbase * K;
    const signed char* Bg = B + (size_t)nbase * K;

    // stage one K-tile (A 16KB + B 16KB): LDS linear, source inverse-swizzled.
    // dest granule j = r*4+gg holds global k-granule gg^(r&3).  Per-wave dest
    // = uniform base + lane*16 (required by global_load_lds).
    auto stage = [&](int buf, int kt) {
        #pragma unroll
        for (int i = 0; i < 2; ++i) {
            int j = i * 512 + t;
            int r = j >> 2, gg = j & 3;
            int kg = gg ^ (r & 3);
            __builtin_amdgcn_global_load_lds(AS1(Ag + (size_t)r * K + kt * 64 + kg * 16),
                                             AS3(&lds[buf][0][0] + j * 16), 16, 0, 0);
        }
        #pragma unroll
        for (int i = 0; i < 2; ++i) {
            int j = i * 512 + t;
            int r = j >> 2, gg = j & 3;
            int kg = gg ^ (r & 3);
            __builtin_amdgcn_global_load_lds(AS1(Bg + (size_t)r * K + kt * 64 + kg * 16),
                                             AS3(&lds[buf][1][0] + j * 16), 16, 0, 0);
        }
    };

    v16i acc[4][2] = {};

    stage(0, 0);
    __syncthreads();                       // drains vmcnt(0): tile 0 landed

    #pragma unroll 1
    for (int kt2 = 0; kt2 < NKT / 2; ++kt2) {
        int kt = kt2 * 2;
        stage(1, kt + 1);                  // prefetch odd tile while computing even
        COMPUTE(0)
        __syncthreads();                   // drain: tile kt+1 landed; buf0 free
        if (kt + 2 < NKT) stage(0, kt + 2);
        COMPUTE(1)
        __syncthreads();
    }

    float wmean = fmaxf((float)wsum[0] * (1.0f / 1048576.0f), 1e-5f);
    size_t rowb = mbase + (size_t)wr * 128;   // + m*32 + (reg&3)+8*(reg>>2)+4*lh
    int    colb = nbase + wc * 64;            // + n*32 + lr

    if constexpr (EPI == 2) {
        #pragma unroll
        for (int m = 0; m < 4; ++m)
            #pragma unroll
            for (int reg = 0; reg < 16; ++reg) {
                size_t grow = rowb + m * 32 + (reg & 3) + 8 * (reg >> 2) + 4 * lh;
                float f = rowscale[grow] * wmean;
                #pragma unroll
                for (int n = 0; n < 2; ++n)
                    out[grow * N + colb + n * 32 + lr] = (float)acc[m][n][reg] * f;
            }
    } else {
        float gv[2];
        #pragma unroll
        for (int n = 0; n < 2; ++n) gv[n] = g[colb + n * 32 + lr];

        if constexpr (EPI == 0) {
            #pragma unroll
            for (int m = 0; m < 4; ++m)
                #pragma unroll
                for (int reg = 0; reg < 16; ++reg) {
                    size_t grow = rowb + m * 32 + (reg & 3) + 8 * (reg >> 2) + 4 * lh;
                    float f = rowscale[grow] * wmean;
                    float ss = 0.f, mx = 0.f;
                    #pragma unroll
                    for (int n = 0; n < 2; ++n) {
                        float z = (float)acc[m][n][reg] * f;
                        float a = fmaxf(z, 0.f);
                        float h = a * a;
                        ss += h * h;
                        mx  = fmaxf(mx, fabsf(h * gv[n]));
                    }
                    // reduce over cols: lanes 0-31 (row R) and 32-63 (row R+4)
                    // reduce independently under xor offsets < 32.
                    #pragma unroll
                    for (int off = 1; off < 32; off <<= 1) {
                        ss += __shfl_xor(ss, off);
                        mx  = fmaxf(mx, __shfl_xor(mx, off));
                    }
                    if (lr == 0) {
                        st_ss[grow * 32 + nt * 4 + wc] = ss;
                        st_mm[grow * 32 + nt * 4 + wc] = mx;
                    }
                }
        } else {  // EPI == 1
            #pragma unroll
            for (int m = 0; m < 4; ++m)
                #pragma unroll
                for (int reg = 0; reg < 16; ++reg) {
                    size_t grow = rowb + m * 32 + (reg & 3) + 8 * (reg >> 2) + 4 * lh;
                    float f  = rowscale[grow] * wmean;
                    float rq = rsq[grow];
                    float sc = s2[grow];
                    #pragma unroll
                    for (int n = 0; n < 2; ++n) {
                        float z = (float)acc[m][n][reg] * f;
                        float a = fmaxf(z, 0.f);
                        float h = a * a;
                        float y = (h * rq) * gv[n];
                        int qv = (int)fminf(fmaxf(rintf(y * sc), -128.f), 127.f);
                        hq[grow * 2048 + colb + n * 32 + lr] = (signed char)qv;
                    }
                }
        }
    }
}

// ---------------------------------------------------------------------------
extern "C" void kernel_launch(void* const* d_in, const int* in_sizes, int n_in,
                              void* d_out, int out_size, void* d_ws, size_t ws_size,
                              hipStream_t stream)
{
    const float* x  = (const float*)d_in[0];
    const float* wu = (const float*)d_in[1];
    const float* wd = (const float*)d_in[2];
    const float* g  = (const float*)d_in[3];
    float* out = (float*)d_out;
    char*  ws  = (char*)d_ws;

    double* sums     = (double*)ws;
    double* part     = (double*)(ws + OFF_PART);
    float*  inv_sx   = (float*)(ws + OFF_SX);
    float*  rsq      = (float*)(ws + OFF_RSQ);
    float*  s2       = (float*)(ws + OFF_S2);
    float*  inv2     = (float*)(ws + OFF_INV2);
    signed char* wuq = (signed char*)(ws + OFF_WUQ);
    signed char* wdq = (signed char*)(ws + OFF_WDQ);
    signed char* xq  = (signed char*)(ws + OFF_XQ);
    signed char* hq  = (signed char*)(ws + OFF_HQ);
    float*  st_ss    = (float*)(ws + OFF_SS);
    float*  st_mm    = (float*)(ws + OFF_MM);

    wabs_partial<<<256, 256, 0, stream>>>(wu, part);
    wabs_partial<<<256, 256, 0, stream>>>(wd, part + 256);
    finalize_sums<<<1, 256, 0, stream>>>(part, sums);
    wquant<<<1024, 256, 0, stream>>>(wu, sums + 0, wuq);
    wquant<<<1024, 256, 0, stream>>>(wd, sums + 1, wdq);
    xquant<<<16384, 256, 0, stream>>>(x, xq, inv_sx);

    // GEMM1 pass A: stats only
    gemm_i8<512, 2048, 0><<<2048, 512, 0, stream>>>(xq, wuq, inv_sx, sums + 0, g,
                                                    nullptr, nullptr, st_ss, st_mm,
                                                    nullptr, nullptr);
    row_reduce<<<256, 256, 0, stream>>>(st_ss, st_mm, rsq, s2, inv2);
    // GEMM1 pass B: fused relu^2 + SubLN + act_quant -> h_q
    gemm_i8<512, 2048, 1><<<2048, 512, 0, stream>>>(xq, wuq, inv_sx, sums + 0, g,
                                                    rsq, s2, nullptr, nullptr,
                                                    hq, nullptr);
    // GEMM2: h_q @ w_down^T -> out
    gemm_i8<2048, 512, 2><<<512, 512, 0, stream>>>(hq, wdq, inv2, sums + 1,
                                                   nullptr, nullptr, nullptr,
                                                   nullptr, nullptr, nullptr, out);
}

// Round 5
// 521.390 us; speedup vs baseline: 1.3304x; 1.3304x over previous
//
#include <hip/hip_runtime.h>
#include <stdint.h>

// BitNet MLP, chunked over tokens (4 x 16384 rows; all ops row-separable):
//   xquant -> [per chunk] GEMM1(int8, writes RAW z int16, exact)
//                         norm_quant (stats + relu^2 + SubLN + act_quant)
//                         GEMM2(int8 -> fp32 out)
// GEMM = round-2 proven structure (128^2 tile, 4 waves, 16x16x64 i8 MFMA,
// single-buffer 2-phase) with corrected conflict-free swizzle g^((r>>1)&3).

typedef int v4i __attribute__((ext_vector_type(4)));

#define AS1(p) ((const __attribute__((address_space(1))) void*)(p))
#define AS3(p) ((__attribute__((address_space(3))) void*)(p))

static constexpr int CHUNK = 16384;                 // rows per chunk (x4)
static constexpr size_t OFF_PART = 256;
static constexpr size_t OFF_SX   = 8192;
static constexpr size_t OFF_INV2 = OFF_SX   + 262144;
static constexpr size_t OFF_WUQ  = OFF_INV2 + 262144;
static constexpr size_t OFF_WDQ  = OFF_WUQ  + 1048576;
static constexpr size_t OFF_XQ   = OFF_WDQ  + 1048576;
static constexpr size_t OFF_Z16  = OFF_XQ   + 33554432;   // 16384*2048*2 = 64 MB
static constexpr size_t OFF_HQ   = OFF_Z16  + 67108864;   // 16384*2048   = 32 MB
// total ~137 MB (< 179 MB proven in rounds 2-4)

// ---------------- weight |w| partial sums (deterministic, fp64) -------------
__global__ void wabs_partial(const float* __restrict__ w, double* __restrict__ part)
{
    int t = threadIdx.x, bid = blockIdx.x;
    const float4* w4 = (const float4*)w;
    int base = bid * 256 + t;
    double s = 0.0;
    #pragma unroll
    for (int j = 0; j < 4; ++j) {
        float4 v = w4[base + j * 65536];
        s += (double)fabsf(v.x) + (double)fabsf(v.y)
           + (double)fabsf(v.z) + (double)fabsf(v.w);
    }
    #pragma unroll
    for (int off = 32; off > 0; off >>= 1) s += __shfl_down(s, off);
    __shared__ double ps[4];
    int l = t & 63, wv = t >> 6;
    if (l == 0) ps[wv] = s;
    __syncthreads();
    if (t == 0) part[bid] = ((ps[0] + ps[1]) + ps[2]) + ps[3];
}

__global__ void finalize_sums(const double* __restrict__ part, double* __restrict__ sums)
{
    int t = threadIdx.x;
    double a = part[t];
    double b = part[256 + t];
    #pragma unroll
    for (int off = 32; off > 0; off >>= 1) {
        a += __shfl_down(a, off);
        b += __shfl_down(b, off);
    }
    __shared__ double pa[4], pb[4];
    int l = t & 63, wv = t >> 6;
    if (l == 0) { pa[wv] = a; pb[wv] = b; }
    __syncthreads();
    if (t == 0) {
        sums[0] = ((pa[0] + pa[1]) + pa[2]) + pa[3];
        sums[1] = ((pb[0] + pb[1]) + pb[2]) + pb[3];
    }
}

// ---------------- ternary weight quantization -------------------------------
__global__ void wquant(const float* __restrict__ w, const double* __restrict__ sum,
                       signed char* __restrict__ wq)
{
    int i = blockIdx.x * blockDim.x + threadIdx.x;
    if (i >= 262144) return;
    float mean  = (float)(*sum) * (1.0f / 1048576.0f);
    float scale = 1.0f / fmaxf(mean, 1e-5f);
    float4 v = ((const float4*)w)[i];
    int q0 = (int)fminf(fmaxf(rintf(v.x * scale), -1.f), 1.f);
    int q1 = (int)fminf(fmaxf(rintf(v.y * scale), -1.f), 1.f);
    int q2 = (int)fminf(fmaxf(rintf(v.z * scale), -1.f), 1.f);
    int q3 = (int)fminf(fmaxf(rintf(v.w * scale), -1.f), 1.f);
    unsigned pk = (q0 & 255) | ((q1 & 255) << 8) | ((q2 & 255) << 16) | ((q3 & 255) << 24);
    ((unsigned*)wq)[i] = pk;
}

// ---------------- activation quantization of x (per-token, H=512) -----------
__global__ void xquant(const float* __restrict__ x, signed char* __restrict__ xq,
                       float* __restrict__ inv_sx)
{
    int row = blockIdx.x * 4 + (threadIdx.x >> 6);
    int l   = threadIdx.x & 63;
    const float* xr = x + (size_t)row * 512;
    float4 v0 = *(const float4*)(xr + l * 8);
    float4 v1 = *(const float4*)(xr + l * 8 + 4);
    float m = fmaxf(fmaxf(fmaxf(fabsf(v0.x), fabsf(v0.y)), fmaxf(fabsf(v0.z), fabsf(v0.w))),
                    fmaxf(fmaxf(fabsf(v1.x), fabsf(v1.y)), fmaxf(fabsf(v1.z), fabsf(v1.w))));
    #pragma unroll
    for (int off = 1; off < 64; off <<= 1) m = fmaxf(m, __shfl_xor(m, off));
    float mc = fmaxf(m, 1e-5f);
    float s  = 127.0f / mc;
    int q[8];
    q[0] = (int)fminf(fmaxf(rintf(v0.x * s), -128.f), 127.f);
    q[1] = (int)fminf(fmaxf(rintf(v0.y * s), -128.f), 127.f);
    q[2] = (int)fminf(fmaxf(rintf(v0.z * s), -128.f), 127.f);
    q[3] = (int)fminf(fmaxf(rintf(v0.w * s), -128.f), 127.f);
    q[4] = (int)fminf(fmaxf(rintf(v1.x * s), -128.f), 127.f);
    q[5] = (int)fminf(fmaxf(rintf(v1.y * s), -128.f), 127.f);
    q[6] = (int)fminf(fmaxf(rintf(v1.z * s), -128.f), 127.f);
    q[7] = (int)fminf(fmaxf(rintf(v1.w * s), -128.f), 127.f);
    uint2 pk;
    pk.x = (q[0] & 255) | ((q[1] & 255) << 8) | ((q[2] & 255) << 16) | ((q[3] & 255) << 24);
    pk.y = (q[4] & 255) | ((q[5] & 255) << 8) | ((q[6] & 255) << 16) | ((q[7] & 255) << 24);
    *(uint2*)(xq + (size_t)row * 512 + l * 8) = pk;
    if (l == 0) inv_sx[row] = mc * (1.0f / 127.0f);
}

// ---------------- fused: stats + relu^2 + SubLN + act_quant -----------------
// One block per token row. z16 holds the EXACT int32 GEMM1 accumulator
// (|z| << 32767 for this data). h = relu(z*f)^2; var = mean(h^2);
// y = h*rsq*g; hq = clamp(round(y*127/max|y|)).
__global__ __launch_bounds__(256)
void norm_quant(const short* __restrict__ z16, const float* __restrict__ inv_sx,
                const double* __restrict__ wsum, const float* __restrict__ g,
                signed char* __restrict__ hq, float* __restrict__ inv2)
{
    int row = blockIdx.x;
    int t = threadIdx.x;
    float wmean = fmaxf((float)wsum[0] * (1.0f / 1048576.0f), 1e-5f);
    float f = inv_sx[row] * wmean;

    v4i zi = *(const v4i*)(z16 + (size_t)row * 2048 + t * 8);  // 8 int16
    const short* zs = (const short*)&zi;
    float4 g0 = *(const float4*)(g + t * 8);
    float4 g1 = *(const float4*)(g + t * 8 + 4);
    float gv[8] = {g0.x, g0.y, g0.z, g0.w, g1.x, g1.y, g1.z, g1.w};

    float h[8];
    float ss = 0.f, mm = 0.f;
    #pragma unroll
    for (int j = 0; j < 8; ++j) {
        float z = (float)zs[j] * f;
        float a = fmaxf(z, 0.f);
        h[j] = a * a;
        ss += h[j] * h[j];
        mm  = fmaxf(mm, fabsf(h[j] * gv[j]));
    }
    #pragma unroll
    for (int off = 1; off < 64; off <<= 1) {
        ss += __shfl_xor(ss, off);
        mm  = fmaxf(mm, __shfl_xor(mm, off));
    }
    __shared__ float sss[4], smm[4];
    int l = t & 63, wv = t >> 6;
    if (l == 0) { sss[wv] = ss; smm[wv] = mm; }
    __syncthreads();
    float sst = ((sss[0] + sss[1]) + sss[2]) + sss[3];
    float mmt = fmaxf(fmaxf(smm[0], smm[1]), fmaxf(smm[2], smm[3]));

    float var  = sst * (1.0f / 2048.0f);
    float r    = 1.0f / sqrtf(var + 1e-6f);
    float maxy = fmaxf(r * mmt, 1e-5f);
    float sc   = 127.0f / maxy;
    if (t == 0) inv2[row] = maxy * (1.0f / 127.0f);

    int q[8];
    #pragma unroll
    for (int j = 0; j < 8; ++j) {
        float y = (h[j] * r) * gv[j];
        q[j] = (int)fminf(fmaxf(rintf(y * sc), -128.f), 127.f);
    }
    uint2 pk;
    pk.x = (q[0] & 255) | ((q[1] & 255) << 8) | ((q[2] & 255) << 16) | ((q[3] & 255) << 24);
    pk.y = (q[4] & 255) | ((q[5] & 255) << 8) | ((q[6] & 255) << 16) | ((q[7] & 255) << 24);
    *(uint2*)(hq + (size_t)row * 2048 + t * 8) = pk;
}

// ---------------- int8 GEMM: C[M,N] = A[M,K] * B[N,K]^T ---------------------
// Round-2 proven structure; swizzle fixed to g^((r>>1)&3) (conflict-free:
// 8 consecutive lanes cover all 32 banks exactly once).
// EPI 0: write raw acc as int16 via LDS transpose (coalesced dwordx4).
// EPI 2: dequant -> fp32 out.
template<int K, int N, int EPI>
__global__ __launch_bounds__(256, 2)
void gemm_i8(const signed char* __restrict__ A,
             const signed char* __restrict__ B,
             const float* __restrict__ rowscale,   // inv2 (EPI2)
             const double* __restrict__ wsum,
             short* __restrict__ z16,
             float* __restrict__ out)
{
    constexpr int NBN = N / 128;
    __shared__ __align__(16) char smem[32768];
    char* lA = smem;
    char* lB = smem + 8192;

    // bijective XCD-chunked swizzle (m204); N-inner so chunks share A panels
    int nwg  = gridDim.x;
    int orig = blockIdx.x;
    int q8 = nwg >> 3, r8 = nwg & 7;
    int xcd = orig & 7, lin = orig >> 3;
    int swz = (xcd < r8 ? xcd * (q8 + 1) : r8 * (q8 + 1) + (xcd - r8) * q8) + lin;
    int mt = swz / NBN, nt = swz - mt * NBN;

    size_t mbase = (size_t)mt * 128;
    int    nbase = nt * 128;

    int t = threadIdx.x;
    int l = t & 63;
    int wid = t >> 6;
    int wr = wid >> 1, wc = wid & 1;

    v4i acc[4][4] = {};

    const signed char* Ab = A + mbase * K;
    const signed char* Bb = B + (size_t)nbase * K;

    for (int k0 = 0; k0 < K; k0 += 64) {
        // stage 128x64 tiles; LDS dest linear, global source inverse-swizzled
        // (16B-granule c XOR (row>>1)&3); swizzled ds_read undoes it.
        #pragma unroll
        for (int i = 0; i < 2; ++i) {
            int lin16 = i * 256 + t;
            int row   = lin16 >> 2;
            int c     = (lin16 & 3) ^ ((row >> 1) & 3);
            __builtin_amdgcn_global_load_lds(AS1(Ab + (size_t)row * K + k0 + c * 16),
                                             AS3(lA + lin16 * 16), 16, 0, 0);
            __builtin_amdgcn_global_load_lds(AS1(Bb + (size_t)row * K + k0 + c * 16),
                                             AS3(lB + lin16 * 16), 16, 0, 0);
        }
        __syncthreads();
        v4i af[4], bf[4];
        #pragma unroll
        for (int r = 0; r < 4; ++r) {
            int arow = wr * 64 + r * 16 + (l & 15);
            int ac   = (l >> 4) ^ ((arow >> 1) & 3);
            af[r] = *reinterpret_cast<const v4i*>(lA + (arow * 4 + ac) * 16);
            int brow = wc * 64 + r * 16 + (l & 15);
            int bc   = (l >> 4) ^ ((brow >> 1) & 3);
            bf[r] = *reinterpret_cast<const v4i*>(lB + (brow * 4 + bc) * 16);
        }
        #pragma unroll
        for (int r = 0; r < 4; ++r)
            #pragma unroll
            for (int c = 0; c < 4; ++c)
                acc[r][c] = __builtin_amdgcn_mfma_i32_16x16x64_i8(af[r], bf[c], acc[r][c], 0, 0, 0);
        __syncthreads();
    }

    int rsub = wr * 64 + 4 * (l >> 4);   // + rt*16 + reg  -> local row
    int csub = wc * 64 + (l & 15);       // + ct*16        -> local col

    if constexpr (EPI == 0) {
        // raw int16 z via LDS transpose -> coalesced 16B stores
        short* sm = (short*)smem;
        #pragma unroll
        for (int rt = 0; rt < 4; ++rt)
            #pragma unroll
            for (int reg = 0; reg < 4; ++reg) {
                int rho = rsub + rt * 16 + reg;
                #pragma unroll
                for (int ct = 0; ct < 4; ++ct)
                    sm[rho * 128 + csub + ct * 16] = (short)acc[rt][ct][reg];
            }
        __syncthreads();
        #pragma unroll
        for (int it = 0; it < 8; ++it) {
            int j = it * 256 + t;
            int rho = j >> 4, ck = j & 15;
            *(v4i*)(z16 + (size_t)(mbase + rho) * 2048 + nbase + ck * 8) =
                *(const v4i*)(sm + rho * 128 + ck * 8);
        }
    } else {
        float wmean = fmaxf((float)wsum[0] * (1.0f / 1048576.0f), 1e-5f);
        #pragma unroll
        for (int rt = 0; rt < 4; ++rt)
            #pragma unroll
            for (int reg = 0; reg < 4; ++reg) {
                size_t grow = mbase + rsub + rt * 16 + reg;
                float f = rowscale[grow] * wmean;
                #pragma unroll
                for (int ct = 0; ct < 4; ++ct)
                    out[grow * N + nbase + csub + ct * 16] = (float)acc[rt][ct][reg] * f;
            }
    }
}

// ---------------------------------------------------------------------------
extern "C" void kernel_launch(void* const* d_in, const int* in_sizes, int n_in,
                              void* d_out, int out_size, void* d_ws, size_t ws_size,
                              hipStream_t stream)
{
    const float* x  = (const float*)d_in[0];
    const float* wu = (const float*)d_in[1];
    const float* wd = (const float*)d_in[2];
    const float* g  = (const float*)d_in[3];
    float* out = (float*)d_out;
    char*  ws  = (char*)d_ws;

    double* sums     = (double*)ws;
    double* part     = (double*)(ws + OFF_PART);
    float*  inv_sx   = (float*)(ws + OFF_SX);
    float*  inv2     = (float*)(ws + OFF_INV2);
    signed char* wuq = (signed char*)(ws + OFF_WUQ);
    signed char* wdq = (signed char*)(ws + OFF_WDQ);
    signed char* xq  = (signed char*)(ws + OFF_XQ);
    short*  z16      = (short*)(ws + OFF_Z16);
    signed char* hq  = (signed char*)(ws + OFF_HQ);

    wabs_partial<<<256, 256, 0, stream>>>(wu, part);
    wabs_partial<<<256, 256, 0, stream>>>(wd, part + 256);
    finalize_sums<<<1, 256, 0, stream>>>(part, sums);
    wquant<<<1024, 256, 0, stream>>>(wu, sums + 0, wuq);
    wquant<<<1024, 256, 0, stream>>>(wd, sums + 1, wdq);
    xquant<<<16384, 256, 0, stream>>>(x, xq, inv_sx);

    for (int c = 0; c < 4; ++c) {
        size_t R = (size_t)c * CHUNK;
        // GEMM1: z = xq @ wuq^T (raw int16, exact)
        gemm_i8<512, 2048, 0><<<(CHUNK / 128) * 16, 256, 0, stream>>>(
            xq + R * 512, wuq, nullptr, nullptr, z16, nullptr);
        // fused stats + relu^2 + SubLN + act_quant
        norm_quant<<<CHUNK, 256, 0, stream>>>(z16, inv_sx + R, sums + 0, g,
                                              hq, inv2 + R);
        // GEMM2: out = hq @ wdq^T, dequant
        gemm_i8<2048, 512, 2><<<(CHUNK / 128) * 4, 256, 0, stream>>>(
            hq, wdq, inv2 + R, sums + 1, nullptr, out + R * 512);
    }
}

// Round 9
// 505.594 us; speedup vs baseline: 1.3720x; 1.0312x over previous
//
#include <hip/hip_runtime.h>
#include <stdint.h>

// BitNet MLP, chunked over tokens (2 x 32768 rows; all ops row-separable):
//   xquant -> [per chunk] GEMM1(int8 -> RAW z int16, exact)
//                         norm_quant (stats + relu^2 + SubLN + act_quant)
//                         GEMM2(int8 -> fp32 out)
// GEMM: 128^2 tile, 4 waves, 16x16x64 i8 MFMA, conflict-free swizzle
// g^((r>>1)&3), prefetch double-buffer (stage k+1 before compute k,
// ONE barrier per K-step whose vmcnt(0) drain is the prefetch wait) +
// launch_bounds(256,4) for ~4 blocks/CU latency hiding.

typedef int v4i __attribute__((ext_vector_type(4)));

#define AS1(p) ((const __attribute__((address_space(1))) void*)(p))
#define AS3(p) ((__attribute__((address_space(3))) void*)(p))

static constexpr int CHUNK = 32768;                 // rows per chunk (x2)
static constexpr size_t OFF_PART = 256;
static constexpr size_t OFF_SX   = 8192;
static constexpr size_t OFF_INV2 = OFF_SX   + 262144;
static constexpr size_t OFF_WUQ  = OFF_INV2 + 262144;
static constexpr size_t OFF_WDQ  = OFF_WUQ  + 1048576;
static constexpr size_t OFF_XQ   = OFF_WDQ  + 1048576;
static constexpr size_t OFF_Z16  = OFF_XQ   + 33554432;   // 32768*2048*2 = 128 MB
static constexpr size_t OFF_HQ   = OFF_Z16  + 134217728;  // 32768*2048   = 64 MB
// total ~229 MB (< 512 MiB ws, evidenced by the 512 MiB poison fills)

// ---------------- weight |w| partial sums (deterministic, fp64) -------------
__global__ void wabs_partial(const float* __restrict__ w, double* __restrict__ part)
{
    int t = threadIdx.x, bid = blockIdx.x;
    const float4* w4 = (const float4*)w;
    int base = bid * 256 + t;
    double s = 0.0;
    #pragma unroll
    for (int j = 0; j < 4; ++j) {
        float4 v = w4[base + j * 65536];
        s += (double)fabsf(v.x) + (double)fabsf(v.y)
           + (double)fabsf(v.z) + (double)fabsf(v.w);
    }
    #pragma unroll
    for (int off = 32; off > 0; off >>= 1) s += __shfl_down(s, off);
    __shared__ double ps[4];
    int l = t & 63, wv = t >> 6;
    if (l == 0) ps[wv] = s;
    __syncthreads();
    if (t == 0) part[bid] = ((ps[0] + ps[1]) + ps[2]) + ps[3];
}

__global__ void finalize_sums(const double* __restrict__ part, double* __restrict__ sums)
{
    int t = threadIdx.x;
    double a = part[t];
    double b = part[256 + t];
    #pragma unroll
    for (int off = 32; off > 0; off >>= 1) {
        a += __shfl_down(a, off);
        b += __shfl_down(b, off);
    }
    __shared__ double pa[4], pb[4];
    int l = t & 63, wv = t >> 6;
    if (l == 0) { pa[wv] = a; pb[wv] = b; }
    __syncthreads();
    if (t == 0) {
        sums[0] = ((pa[0] + pa[1]) + pa[2]) + pa[3];
        sums[1] = ((pb[0] + pb[1]) + pb[2]) + pb[3];
    }
}

// ---------------- ternary weight quantization -------------------------------
__global__ void wquant(const float* __restrict__ w, const double* __restrict__ sum,
                       signed char* __restrict__ wq)
{
    int i = blockIdx.x * blockDim.x + threadIdx.x;
    if (i >= 262144) return;
    float mean  = (float)(*sum) * (1.0f / 1048576.0f);
    float scale = 1.0f / fmaxf(mean, 1e-5f);
    float4 v = ((const float4*)w)[i];
    int q0 = (int)fminf(fmaxf(rintf(v.x * scale), -1.f), 1.f);
    int q1 = (int)fminf(fmaxf(rintf(v.y * scale), -1.f), 1.f);
    int q2 = (int)fminf(fmaxf(rintf(v.z * scale), -1.f), 1.f);
    int q3 = (int)fminf(fmaxf(rintf(v.w * scale), -1.f), 1.f);
    unsigned pk = (q0 & 255) | ((q1 & 255) << 8) | ((q2 & 255) << 16) | ((q3 & 255) << 24);
    ((unsigned*)wq)[i] = pk;
}

// ---------------- activation quantization of x (per-token, H=512) -----------
__global__ void xquant(const float* __restrict__ x, signed char* __restrict__ xq,
                       float* __restrict__ inv_sx)
{
    int row = blockIdx.x * 4 + (threadIdx.x >> 6);
    int l   = threadIdx.x & 63;
    const float* xr = x + (size_t)row * 512;
    float4 v0 = *(const float4*)(xr + l * 8);
    float4 v1 = *(const float4*)(xr + l * 8 + 4);
    float m = fmaxf(fmaxf(fmaxf(fabsf(v0.x), fabsf(v0.y)), fmaxf(fabsf(v0.z), fabsf(v0.w))),
                    fmaxf(fmaxf(fabsf(v1.x), fabsf(v1.y)), fmaxf(fabsf(v1.z), fabsf(v1.w))));
    #pragma unroll
    for (int off = 1; off < 64; off <<= 1) m = fmaxf(m, __shfl_xor(m, off));
    float mc = fmaxf(m, 1e-5f);
    float s  = 127.0f / mc;
    int q[8];
    q[0] = (int)fminf(fmaxf(rintf(v0.x * s), -128.f), 127.f);
    q[1] = (int)fminf(fmaxf(rintf(v0.y * s), -128.f), 127.f);
    q[2] = (int)fminf(fmaxf(rintf(v0.z * s), -128.f), 127.f);
    q[3] = (int)fminf(fmaxf(rintf(v0.w * s), -128.f), 127.f);
    q[4] = (int)fminf(fmaxf(rintf(v1.x * s), -128.f), 127.f);
    q[5] = (int)fminf(fmaxf(rintf(v1.y * s), -128.f), 127.f);
    q[6] = (int)fminf(fmaxf(rintf(v1.z * s), -128.f), 127.f);
    q[7] = (int)fminf(fmaxf(rintf(v1.w * s), -128.f), 127.f);
    uint2 pk;
    pk.x = (q[0] & 255) | ((q[1] & 255) << 8) | ((q[2] & 255) << 16) | ((q[3] & 255) << 24);
    pk.y = (q[4] & 255) | ((q[5] & 255) << 8) | ((q[6] & 255) << 16) | ((q[7] & 255) << 24);
    *(uint2*)(xq + (size_t)row * 512 + l * 8) = pk;
    if (l == 0) inv_sx[row] = mc * (1.0f / 127.0f);
}

// ---------------- fused: stats + relu^2 + SubLN + act_quant -----------------
__global__ __launch_bounds__(256)
void norm_quant(const short* __restrict__ z16, const float* __restrict__ inv_sx,
                const double* __restrict__ wsum, const float* __restrict__ g,
                signed char* __restrict__ hq, float* __restrict__ inv2)
{
    int row = blockIdx.x;
    int t = threadIdx.x;
    float wmean = fmaxf((float)wsum[0] * (1.0f / 1048576.0f), 1e-5f);
    float f = inv_sx[row] * wmean;

    v4i zi = *(const v4i*)(z16 + (size_t)row * 2048 + t * 8);  // 8 int16
    const short* zs = (const short*)&zi;
    float4 g0 = *(const float4*)(g + t * 8);
    float4 g1 = *(const float4*)(g + t * 8 + 4);
    float gv[8] = {g0.x, g0.y, g0.z, g0.w, g1.x, g1.y, g1.z, g1.w};

    float h[8];
    float ss = 0.f, mm = 0.f;
    #pragma unroll
    for (int j = 0; j < 8; ++j) {
        float z = (float)zs[j] * f;
        float a = fmaxf(z, 0.f);
        h[j] = a * a;
        ss += h[j] * h[j];
        mm  = fmaxf(mm, fabsf(h[j] * gv[j]));
    }
    #pragma unroll
    for (int off = 1; off < 64; off <<= 1) {
        ss += __shfl_xor(ss, off);
        mm  = fmaxf(mm, __shfl_xor(mm, off));
    }
    __shared__ float sss[4], smm[4];
    int l = t & 63, wv = t >> 6;
    if (l == 0) { sss[wv] = ss; smm[wv] = mm; }
    __syncthreads();
    float sst = ((sss[0] + sss[1]) + sss[2]) + sss[3];
    float mmt = fmaxf(fmaxf(smm[0], smm[1]), fmaxf(smm[2], smm[3]));

    float var  = sst * (1.0f / 2048.0f);
    float r    = 1.0f / sqrtf(var + 1e-6f);
    float maxy = fmaxf(r * mmt, 1e-5f);
    float sc   = 127.0f / maxy;
    if (t == 0) inv2[row] = maxy * (1.0f / 127.0f);

    int q[8];
    #pragma unroll
    for (int j = 0; j < 8; ++j) {
        float y = (h[j] * r) * gv[j];
        q[j] = (int)fminf(fmaxf(rintf(y * sc), -128.f), 127.f);
    }
    uint2 pk;
    pk.x = (q[0] & 255) | ((q[1] & 255) << 8) | ((q[2] & 255) << 16) | ((q[3] & 255) << 24);
    pk.y = (q[4] & 255) | ((q[5] & 255) << 8) | ((q[6] & 255) << 16) | ((q[7] & 255) << 24);
    *(uint2*)(hq + (size_t)row * 2048 + t * 8) = pk;
}

// ---------------- int8 GEMM: C[M,N] = A[M,K] * B[N,K]^T ---------------------
// Prefetch double-buffer: stage(kt+1) issued BEFORE compute(kt); one
// __syncthreads per K-step (its vmcnt(0)+lgkmcnt(0) drain IS the prefetch
// wait).  RAW: iter k's ds_reads covered by iter k-1's drain.  WAR: stage
// overwrites a buffer last read 1 iter ago, behind a barrier.
// EPI 0: raw acc -> int16 via LDS transpose.  EPI 2: dequant -> fp32.
template<int K, int N, int EPI>
__global__ __launch_bounds__(256, 4)
void gemm_i8(const signed char* __restrict__ A,
             const signed char* __restrict__ B,
             const float* __restrict__ rowscale,   // inv2 (EPI2)
             const double* __restrict__ wsum,
             short* __restrict__ z16,
             float* __restrict__ out)
{
    constexpr int NKT = K / 64;
    constexpr int NBN = N / 128;
    __shared__ __align__(16) char smem[32768];     // 2 bufs x (A 8K + B 8K)

    // bijective XCD-chunked swizzle (m204); N-inner so chunks share A panels
    int nwg  = gridDim.x;
    int orig = blockIdx.x;
    int q8 = nwg >> 3, r8 = nwg & 7;
    int xcd = orig & 7, lin = orig >> 3;
    int swz = (xcd < r8 ? xcd * (q8 + 1) : r8 * (q8 + 1) + (xcd - r8) * q8) + lin;
    int mt = swz / NBN, nt = swz - mt * NBN;

    size_t mbase = (size_t)mt * 128;
    int    nbase = nt * 128;

    int t = threadIdx.x;
    int l = t & 63;
    int wid = t >> 6;
    int wr = wid >> 1, wc = wid & 1;

    v4i acc[4][4] = {};

    const signed char* Ab = A + mbase * K;
    const signed char* Bb = B + (size_t)nbase * K;

    // stage K-tile `kt` into buffer p: LDS dest linear, global source
    // inverse-swizzled (granule c XOR (row>>1)&3) -> conflict-free ds_read.
    auto stage = [&](int p, int kt) {
        char* lA = smem + p * 16384;
        char* lB = lA + 8192;
        int k0 = kt * 64;
        #pragma unroll
        for (int i = 0; i < 2; ++i) {
            int lin16 = i * 256 + t;
            int row   = lin16 >> 2;
            int c     = (lin16 & 3) ^ ((row >> 1) & 3);
            __builtin_amdgcn_global_load_lds(AS1(Ab + (size_t)row * K + k0 + c * 16),
                                             AS3(lA + lin16 * 16), 16, 0, 0);
            __builtin_amdgcn_global_load_lds(AS1(Bb + (size_t)row * K + k0 + c * 16),
                                             AS3(lB + lin16 * 16), 16, 0, 0);
        }
    };

    stage(0, 0);
    __syncthreads();                               // tile 0 landed

    for (int kt = 0; kt < NKT; ++kt) {
        int p = kt & 1;
        if (kt + 1 < NKT) stage(p ^ 1, kt + 1);    // prefetch next tile
        const char* lA = smem + p * 16384;
        const char* lB = lA + 8192;
        v4i af[4], bf[4];
        #pragma unroll
        for (int r = 0; r < 4; ++r) {
            int arow = wr * 64 + r * 16 + (l & 15);
            int ac   = (l >> 4) ^ ((arow >> 1) & 3);
            af[r] = *reinterpret_cast<const v4i*>(lA + (arow * 4 + ac) * 16);
            int brow = wc * 64 + r * 16 + (l & 15);
            int bc   = (l >> 4) ^ ((brow >> 1) & 3);
            bf[r] = *reinterpret_cast<const v4i*>(lB + (brow * 4 + bc) * 16);
        }
        #pragma unroll
        for (int r = 0; r < 4; ++r)
            #pragma unroll
            for (int c = 0; c < 4; ++c)
                acc[r][c] = __builtin_amdgcn_mfma_i32_16x16x64_i8(af[r], bf[c], acc[r][c], 0, 0, 0);
        __syncthreads();                           // drains vmcnt: prefetch landed
    }

    int rsub = wr * 64 + 4 * (l >> 4);   // + rt*16 + reg  -> local row
    int csub = wc * 64 + (l & 15);       // + ct*16        -> local col

    if constexpr (EPI == 0) {
        // raw int16 z via LDS transpose -> coalesced 16B stores
        short* sm = (short*)smem;
        #pragma unroll
        for (int rt = 0; rt < 4; ++rt)
            #pragma unroll
            for (int reg = 0; reg < 4; ++reg) {
                int rho = rsub + rt * 16 + reg;
                #pragma unroll
                for (int ct = 0; ct < 4; ++ct)
                    sm[rho * 128 + csub + ct * 16] = (short)acc[rt][ct][reg];
            }
        __syncthreads();
        #pragma unroll
        for (int it = 0; it < 8; ++it) {
            int j = it * 256 + t;
            int rho = j >> 4, ck = j & 15;
            *(v4i*)(z16 + (size_t)(mbase + rho) * 2048 + nbase + ck * 8) =
                *(const v4i*)(sm + rho * 128 + ck * 8);
        }
    } else {
        float wmean = fmaxf((float)wsum[0] * (1.0f / 1048576.0f), 1e-5f);
        #pragma unroll
        for (int rt = 0; rt < 4; ++rt)
            #pragma unroll
            for (int reg = 0; reg < 4; ++reg) {
                size_t grow = mbase + rsub + rt * 16 + reg;
                float f = rowscale[grow] * wmean;
                #pragma unroll
                for (int ct = 0; ct < 4; ++ct)
                    out[grow * N + nbase + csub + ct * 16] = (float)acc[rt][ct][reg] * f;
            }
    }
}

// ---------------------------------------------------------------------------
extern "C" void kernel_launch(void* const* d_in, const int* in_sizes, int n_in,
                              void* d_out, int out_size, void* d_ws, size_t ws_size,
                              hipStream_t stream)
{
    const float* x  = (const float*)d_in[0];
    const float* wu = (const float*)d_in[1];
    const float* wd = (const float*)d_in[2];
    const float* g  = (const float*)d_in[3];
    float* out = (float*)d_out;
    char*  ws  = (char*)d_ws;

    double* sums     = (double*)ws;
    double* part     = (double*)(ws + OFF_PART);
    float*  inv_sx   = (float*)(ws + OFF_SX);
    float*  inv2     = (float*)(ws + OFF_INV2);
    signed char* wuq = (signed char*)(ws + OFF_WUQ);
    signed char* wdq = (signed char*)(ws + OFF_WDQ);
    signed char* xq  = (signed char*)(ws + OFF_XQ);
    short*  z16      = (short*)(ws + OFF_Z16);
    signed char* hq  = (signed char*)(ws + OFF_HQ);

    wabs_partial<<<256, 256, 0, stream>>>(wu, part);
    wabs_partial<<<256, 256, 0, stream>>>(wd, part + 256);
    finalize_sums<<<1, 256, 0, stream>>>(part, sums);
    wquant<<<1024, 256, 0, stream>>>(wu, sums + 0, wuq);
    wquant<<<1024, 256, 0, stream>>>(wd, sums + 1, wdq);
    xquant<<<16384, 256, 0, stream>>>(x, xq, inv_sx);

    for (int c = 0; c < 2; ++c) {
        size_t R = (size_t)c * CHUNK;
        // GEMM1: z = xq @ wuq^T (raw int16, exact)
        gemm_i8<512, 2048, 0><<<(CHUNK / 128) * 16, 256, 0, stream>>>(
            xq + R * 512, wuq, nullptr, nullptr, z16, nullptr);
        // fused stats + relu^2 + SubLN + act_quant
        norm_quant<<<CHUNK, 256, 0, stream>>>(z16, inv_sx + R, sums + 0, g,
                                              hq, inv2 + R);
        // GEMM2: out = hq @ wdq^T, dequant
        gemm_i8<2048, 512, 2><<<(CHUNK / 128) * 4, 256, 0, stream>>>(
            hq, wdq, inv2 + R, sums + 1, nullptr, out + R * 512);
    }
}